// Round 9
// baseline (593.577 us; speedup 1.0000x reference)
//
#include <hip/hip_runtime.h>
#include <hip/hip_bf16.h>

typedef __hip_bfloat16 bf16;
typedef __bf16 nbf;
typedef nbf bf16x8 __attribute__((ext_vector_type(8)));
typedef float f32x4 __attribute__((ext_vector_type(4)));

#define NNODE 10000
#define DDEG  15
#define EE    320
#define LL    16
#define NH    5
#define HD    64
#define OUTD  30
#define PCOLS 1920   // 6*E : [Qin|Kin|Vin|Qout|Kout|Vout]
#define KF    642    // 2*E + 2 (alpha columns)
#define TST   644    // padded T row stride (16B-aligned f32 rows)

// ---------------------------------------------------------------------------
// dtype detection: bf16 data -> low-16 exponent field clustered in [100,140]
// ---------------------------------------------------------------------------
__global__ void detect_dtype_kernel(const unsigned int* __restrict__ X, int* __restrict__ flag)
{
    __shared__ int cnt;
    if (threadIdx.x == 0) cnt = 0;
    __syncthreads();
    int local = 0;
    for (int i = threadIdx.x; i < 1024; i += 256) {
        unsigned int lo = X[i] & 0xFFFFu;
        int e = (int)((lo >> 7) & 0xFFu);
        if (e >= 100 && e <= 140) local++;
    }
    atomicAdd(&cnt, local);
    __syncthreads();
    if (threadIdx.x == 0) *flag = (cnt > 512) ? 1 : 0;
}

__global__ void convert_bf_kernel(const void* __restrict__ src, nbf* __restrict__ dst,
                                  int n, const int* __restrict__ flag)
{
    int i = blockIdx.x * 256 + threadIdx.x;
    if (i >= n) return;
    if (*flag) dst[i] = ((const nbf*)src)[i];
    else       dst[i] = (nbf)(((const float*)src)[i]);
}

#define NSEG 18
struct ConvTab {
    const void* src[NSEG];
    void*       dst[NSEG];
    int         n[NSEG];
    int         tobf[NSEG];
};

__global__ void convert_batch_kernel(ConvTab t, const int* __restrict__ flag)
{
    const int seg = blockIdx.y;
    const int i = blockIdx.x * 256 + threadIdx.x;
    if (i >= t.n[seg]) return;
    float v = (*flag) ? (float)(((const nbf*)t.src[seg])[i]) : ((const float*)t.src[seg])[i];
    if (t.tobf[seg]) ((nbf*)t.dst[seg])[i] = (nbf)v;
    else             ((float*)t.dst[seg])[i] = v;
}

// 3 batched 320x320 transposes: dst[a][e] = src[e][a] (bf16 out)
__global__ __launch_bounds__(256) void transpose3_kernel(const void* s0, const void* s1,
        const void* s2, nbf* __restrict__ dstbase, const int* __restrict__ flag)
{
    const void* src = (blockIdx.z == 0) ? s0 : (blockIdx.z == 1) ? s1 : s2;
    nbf* dst = dstbase + (size_t)blockIdx.z * EE * EE;
    __shared__ nbf tile[32][33];
    const int bx = blockIdx.x * 32, by = blockIdx.y * 32;
    const int tx = threadIdx.x & 31, ty = threadIdx.x >> 5;
    const int f = *flag;
    #pragma unroll
    for (int i = 0; i < 4; ++i) {
        const int r = by + ty + i * 8;
        float v = f ? (float)(((const nbf*)src)[(long)r * EE + bx + tx])
                    : ((const float*)src)[(long)r * EE + bx + tx];
        tile[ty + i * 8][tx] = (nbf)v;
    }
    __syncthreads();
    #pragma unroll
    for (int i = 0; i < 4; ++i) {
        const int r = bx + ty + i * 8;
        dst[(long)r * EE + by + tx] = tile[tx][ty + i * 8];
    }
}

__device__ __forceinline__ void stor(float* p, float v) { *p = v; }
__device__ __forceinline__ void stor(bf16* p, float v) { *p = __float2bfloat16(v); }

// ---------------------------------------------------------------------------
// VALU 64x64 GEMM (tiny compose ops; f32 in)
// ---------------------------------------------------------------------------
template<bool AT, bool BT, typename OT>
__global__ __launch_bounds__(256) void gemm_k(const float* __restrict__ A, int lda,
                       const float* __restrict__ B, int ldb,
                       const float* __restrict__ bias,
                       OT* __restrict__ C, int ldc, int M, int Nn, int K)
{
    __shared__ float As[16][65];
    __shared__ float Bs[16][65];
    const int tid = threadIdx.x;
    const int tx = tid & 15, ty = tid >> 4;
    const int n0 = blockIdx.x * 64, m0 = blockIdx.y * 64;
    float acc[4][4] = {};
    for (int k0 = 0; k0 < K; k0 += 16) {
        if constexpr (AT) {
            for (int i = tid; i < 1024; i += 256) {
                int kk = i >> 6, r = i & 63;
                int gm = m0 + r, gk = k0 + kk;
                As[kk][r] = (gm < M && gk < K) ? A[(long)gk * lda + gm] : 0.f;
            }
        } else {
            for (int i = tid; i < 1024; i += 256) {
                int r = i >> 4, kk = i & 15;
                int gm = m0 + r, gk = k0 + kk;
                As[kk][r] = (gm < M && gk < K) ? A[(long)gm * lda + gk] : 0.f;
            }
        }
        if constexpr (BT) {
            for (int i = tid; i < 1024; i += 256) {
                int r = i >> 4, kk = i & 15;
                int gn = n0 + r, gk = k0 + kk;
                Bs[kk][r] = (gn < Nn && gk < K) ? B[(long)gn * ldb + gk] : 0.f;
            }
        } else {
            for (int i = tid; i < 1024; i += 256) {
                int kk = i >> 6, c = i & 63;
                int gk = k0 + kk, gn = n0 + c;
                Bs[kk][c] = (gk < K && gn < Nn) ? B[(long)gk * ldb + gn] : 0.f;
            }
        }
        __syncthreads();
        #pragma unroll
        for (int kk = 0; kk < 16; ++kk) {
            float ra[4], rb[4];
            #pragma unroll
            for (int a = 0; a < 4; ++a) ra[a] = As[kk][ty * 4 + a];
            #pragma unroll
            for (int b = 0; b < 4; ++b) rb[b] = Bs[kk][tx * 4 + b];
            #pragma unroll
            for (int a = 0; a < 4; ++a)
                #pragma unroll
                for (int b = 0; b < 4; ++b)
                    acc[a][b] += ra[a] * rb[b];
        }
        __syncthreads();
    }
    #pragma unroll
    for (int a = 0; a < 4; ++a) {
        int gm = m0 + ty * 4 + a;
        if (gm >= M) continue;
        #pragma unroll
        for (int b = 0; b < 4; ++b) {
            int gn = n0 + tx * 4 + b;
            if (gn >= Nn) continue;
            float v = acc[a][b] + (bias ? bias[gn] : 0.f);
            stor(&C[(long)gm * ldc + gn], v);
        }
    }
}

// ---------------------------------------------------------------------------
// MFMA bf16 GEMM: C[M,N] = A[M,K] @ Bt[N,K]^T + bias. 128x128 tile, BK=32.
// ---------------------------------------------------------------------------
template<typename OT>
__global__ __launch_bounds__(256) void gemm_mfma(const nbf* __restrict__ A, int lda,
        const nbf* __restrict__ Bt, int ldb, const float* __restrict__ bias,
        OT* __restrict__ C, int ldc, int M, int Nn, int K)
{
    __shared__ __align__(16) nbf As[128][40];
    __shared__ __align__(16) nbf Bs[128][40];
    const int tid = threadIdx.x;
    const int lane = tid & 63, wave = tid >> 6;
    const int wr = (wave >> 1) * 64, wc = (wave & 1) * 64;
    const int m0 = blockIdx.y * 128, n0 = blockIdx.x * 128;
    const int lr = lane & 15, lq = lane >> 4;
    f32x4 acc[4][4];
    #pragma unroll
    for (int i = 0; i < 4; ++i)
        #pragma unroll
        for (int j = 0; j < 4; ++j) { acc[i][j][0]=0.f; acc[i][j][1]=0.f; acc[i][j][2]=0.f; acc[i][j][3]=0.f; }

    for (int k0 = 0; k0 < K; k0 += 32) {
        #pragma unroll
        for (int v = tid; v < 512; v += 256) {
            const int row = v >> 2, cv = (v & 3) << 3;
            const int gk = k0 + cv;
            {
                const int gm = m0 + row;
                bf16x8 val;
                if (gm < M && gk + 8 <= K) {
                    val = *(const bf16x8*)(A + (long)gm * lda + gk);
                } else {
                    union { bf16x8 v8; nbf e[8]; } u;
                    #pragma unroll
                    for (int j = 0; j < 8; ++j) {
                        float x = (gm < M && gk + j < K) ? (float)A[(long)gm * lda + gk + j] : 0.f;
                        u.e[j] = (nbf)x;
                    }
                    val = u.v8;
                }
                *(bf16x8*)&As[row][cv] = val;
            }
            {
                const int gn = n0 + row;
                bf16x8 val;
                if (gn < Nn && gk + 8 <= K) {
                    val = *(const bf16x8*)(Bt + (long)gn * ldb + gk);
                } else {
                    union { bf16x8 v8; nbf e[8]; } u;
                    #pragma unroll
                    for (int j = 0; j < 8; ++j) {
                        float x = (gn < Nn && gk + j < K) ? (float)Bt[(long)gn * ldb + gk + j] : 0.f;
                        u.e[j] = (nbf)x;
                    }
                    val = u.v8;
                }
                *(bf16x8*)&Bs[row][cv] = val;
            }
        }
        __syncthreads();
        bf16x8 af[4], bfv[4];
        #pragma unroll
        for (int i = 0; i < 4; ++i) af[i] = *(const bf16x8*)&As[wr + i * 16 + lr][lq * 8];
        #pragma unroll
        for (int j = 0; j < 4; ++j) bfv[j] = *(const bf16x8*)&Bs[wc + j * 16 + lr][lq * 8];
        #pragma unroll
        for (int i = 0; i < 4; ++i)
            #pragma unroll
            for (int j = 0; j < 4; ++j)
                acc[i][j] = __builtin_amdgcn_mfma_f32_16x16x32_bf16(af[i], bfv[j], acc[i][j], 0, 0, 0);
        __syncthreads();
    }
    #pragma unroll
    for (int i = 0; i < 4; ++i) {
        #pragma unroll
        for (int j = 0; j < 4; ++j) {
            const int gn = n0 + wc + j * 16 + lr;
            if (gn >= Nn) continue;
            const float bv = bias ? bias[gn] : 0.f;
            #pragma unroll
            for (int r = 0; r < 4; ++r) {
                const int gm = m0 + wr + i * 16 + lq * 4 + r;
                if (gm < M) stor(&C[(long)gm * ldc + gn], acc[i][j][r] + bv);
            }
        }
    }
}

// ---------------------------------------------------------------------------
// Batched 320x320x320 bf16 GEMMs (compose stage 1): C[j] = A[j] @ B[j]^T
// ---------------------------------------------------------------------------
#define NJOB 11
struct JobTab {
    const nbf* A[NJOB];
    const nbf* B[NJOB];
    nbf*       C[NJOB];
};

__global__ __launch_bounds__(256) void gemm_mfma_jobs(JobTab jt)
{
    const nbf* A  = jt.A[blockIdx.z];
    const nbf* Bt = jt.B[blockIdx.z];
    nbf* C        = jt.C[blockIdx.z];
    __shared__ __align__(16) nbf As[128][40];
    __shared__ __align__(16) nbf Bs[128][40];
    const int tid = threadIdx.x;
    const int lane = tid & 63, wave = tid >> 6;
    const int wr = (wave >> 1) * 64, wc = (wave & 1) * 64;
    const int m0 = blockIdx.y * 128, n0 = blockIdx.x * 128;
    const int lr = lane & 15, lq = lane >> 4;
    f32x4 acc[4][4];
    #pragma unroll
    for (int i = 0; i < 4; ++i)
        #pragma unroll
        for (int j = 0; j < 4; ++j) { acc[i][j][0]=0.f; acc[i][j][1]=0.f; acc[i][j][2]=0.f; acc[i][j][3]=0.f; }
    for (int k0 = 0; k0 < EE; k0 += 32) {
        #pragma unroll
        for (int v = tid; v < 512; v += 256) {
            const int row = v >> 2, cv = (v & 3) << 3;
            const int gk = k0 + cv;
            const int gm = m0 + row, gn = n0 + row;
            bf16x8 va = {}, vb = {};
            if (gm < EE) va = *(const bf16x8*)(A + (long)gm * EE + gk);
            if (gn < EE) vb = *(const bf16x8*)(Bt + (long)gn * EE + gk);
            *(bf16x8*)&As[row][cv] = va;
            *(bf16x8*)&Bs[row][cv] = vb;
        }
        __syncthreads();
        bf16x8 af[4], bfv[4];
        #pragma unroll
        for (int i = 0; i < 4; ++i) af[i] = *(const bf16x8*)&As[wr + i * 16 + lr][lq * 8];
        #pragma unroll
        for (int j = 0; j < 4; ++j) bfv[j] = *(const bf16x8*)&Bs[wc + j * 16 + lr][lq * 8];
        #pragma unroll
        for (int i = 0; i < 4; ++i)
            #pragma unroll
            for (int j = 0; j < 4; ++j)
                acc[i][j] = __builtin_amdgcn_mfma_f32_16x16x32_bf16(af[i], bfv[j], acc[i][j], 0, 0, 0);
        __syncthreads();
    }
    #pragma unroll
    for (int i = 0; i < 4; ++i)
        #pragma unroll
        for (int j = 0; j < 4; ++j) {
            const int gn = n0 + wc + j * 16 + lr;
            if (gn >= EE) continue;
            #pragma unroll
            for (int r = 0; r < 4; ++r) {
                const int gm = m0 + wr + i * 16 + lq * 4 + r;
                if (gm < EE) C[(long)gm * EE + gn] = (nbf)acc[i][j][r];
            }
        }
}

// ---------------------------------------------------------------------------
// which: 0->bqc_in  1->Kcat row640  2->Kcat row641  3->VcatN row640  4->row641
// ---------------------------------------------------------------------------
__global__ __launch_bounds__(320) void compose_bias_kernel(
        const float* __restrict__ in_o_b, const float* __restrict__ out_o_b,
        const float* __restrict__ fin_qkv_w, const float* __restrict__ fin_qkv_b,
        float* __restrict__ bqc_in, nbf* __restrict__ Kcat, nbf* __restrict__ VcatN)
{
    const int which = blockIdx.x;
    const int b = threadIdx.x;
    const float* ob = (which == 2 || which == 4) ? out_o_b : in_o_b;
    const int off = (which == 0) ? 0 : (which <= 2) ? 320 : 640;
    float acc = fin_qkv_b[off + b];
    const float* wr = fin_qkv_w + (long)(off + b) * EE;
    for (int e = 0; e < EE; ++e) acc += ob[e] * wr[e];
    if (which == 0)      bqc_in[b] = acc;
    else if (which == 1) Kcat[(long)640 * EE + b] = (nbf)acc;
    else if (which == 2) Kcat[(long)641 * EE + b] = (nbf)acc;
    else if (which == 3) VcatN[(long)640 * EE + b] = (nbf)acc;
    else                 VcatN[(long)641 * EE + b] = (nbf)acc;
}

__global__ void compose_bfin(const float* __restrict__ fin_o_b, const float* __restrict__ W,
                             float* __restrict__ bfin)
{
    int j = threadIdx.x;
    if (j >= OUTD) return;
    float acc = 0.f;
    for (int e = 0; e < EE; ++e) acc += fin_o_b[e] * W[e * OUTD + j];
    bfin[j] = acc;
}

__global__ void compose_bT(const float* __restrict__ bqc, const nbf* __restrict__ Kcat,
                           float* __restrict__ bT)
{
    int c = blockIdx.x * 256 + threadIdx.x;
    if (c >= KF) return;
    const nbf* kr = Kcat + (long)c * EE;
    float acc = 0.f;
    for (int b = 0; b < EE; ++b) acc += bqc[b] * (float)kr[b];
    bT[c] = acc;
}

// Ut[64][320] bf16: rows 0..29 = WWT[:,0:320] (in-proj), 32..61 = WWT[:,320:640]
__global__ void ut_prep_kernel(const float* __restrict__ WWT, nbf* __restrict__ Ut)
{
    int v = blockIdx.x * 256 + threadIdx.x;
    if (v >= 64 * EE) return;
    int n = v / EE, e = v % EE;
    float val = 0.f;
    if (n < OUTD) val = WWT[(long)n * KF + e];
    else if (n >= 32 && n < 32 + OUTD) val = WWT[(long)(n - 32) * KF + 320 + e];
    Ut[v] = (nbf)val;
}

// ---------------------------------------------------------------------------
// row0: per-node single-query in-dir attention -> Orow0[node][320] (bf16)
// One wave per node; 4 waves/block.
// ---------------------------------------------------------------------------
__global__ __launch_bounds__(256) void row0_kernel(const nbf* __restrict__ P,
        const int* __restrict__ in_idx, nbf* __restrict__ Orow0)
{
    const int tid = threadIdx.x, lane = tid & 63, wave = tid >> 6;
    const int node = blockIdx.x * 4 + wave;
    __shared__ float a_sh[4][16];
    __shared__ int srcs_sh[4][16];
    const int m = lane & 15, q4 = lane >> 4;
    const int src = (m == 0) ? node : in_idx[node * DDEG + m - 1];
    if (q4 == 0) srcs_sh[wave][m] = src;
    const nbf* qrow = P + (long)node * PCOLS;
    const nbf* krow = P + (long)src * PCOLS + 320;
    #pragma unroll
    for (int h = 0; h < NH; ++h) {
        float s = 0.f;
        bf16x8 q1 = *(const bf16x8*)(qrow + h * 64 + q4 * 16);
        bf16x8 q2 = *(const bf16x8*)(qrow + h * 64 + q4 * 16 + 8);
        bf16x8 k1 = *(const bf16x8*)(krow + h * 64 + q4 * 16);
        bf16x8 k2 = *(const bf16x8*)(krow + h * 64 + q4 * 16 + 8);
        #pragma unroll
        for (int j = 0; j < 8; ++j)
            s += (float)q1[j] * (float)k1[j] + (float)q2[j] * (float)k2[j];
        s += __shfl_xor(s, 16);
        s += __shfl_xor(s, 32);
        s *= 0.125f;
        float mxv = s;
        #pragma unroll
        for (int msk = 8; msk >= 1; msk >>= 1) mxv = fmaxf(mxv, __shfl_xor(mxv, msk));
        float e = __expf(s - mxv);
        float es = e;
        #pragma unroll
        for (int msk = 8; msk >= 1; msk >>= 1) es += __shfl_xor(es, msk);
        if (q4 == 0) a_sh[wave][m] = e / es;
        // wave-private LDS: same-wave DS ordering makes this visible
        float o = 0.f;
        #pragma unroll
        for (int mm = 0; mm < 16; ++mm)
            o += a_sh[wave][mm] * (float)P[(long)srcs_sh[wave][mm] * PCOLS + 640 + h * 64 + lane];
        Orow0[(long)node * EE + h * 64 + lane] = (nbf)o;
    }
}

// ---------------------------------------------------------------------------
// Mega fused kernel: one block (320 thr = 5 waves) per node.
// Recomputes both dirs' 16-token attention (O kept in LDS, never global),
// s from f32 MFMA outputs vs T row, softmax-32, weighted g, Ut projection.
// ---------------------------------------------------------------------------
__global__ __launch_bounds__(320) void mega_attn_kernel(const nbf* __restrict__ P,
        const int* __restrict__ in_idx, const int* __restrict__ out_idx,
        const float* __restrict__ T, const nbf* __restrict__ Ut,
        const float* __restrict__ WWT, const float* __restrict__ bfin,
        void* __restrict__ out, const int* __restrict__ flag)
{
    const int node = blockIdx.x;
    const int tid = threadIdx.x;
    const int lane = tid & 63, wave = tid >> 6;      // wave == head
    __shared__ __align__(16) nbf o_s[32][328];
    __shared__ __align__(16) nbf v_s[16][328];
    __shared__ __align__(16) nbf p_s[NH][16][16];
    __shared__ float s_red[2][16][8];
    __shared__ float s_fin[32];
    __shared__ float a_s[32];
    __shared__ float g_s[640];
    const int lr = lane & 15, lq = lane >> 4;
    const float* Trow = T + (long)node * TST;

    for (int d = 0; d < 2; ++d) {
        if (d) __syncthreads();                     // all waves done with prev v_s
        const int* idx = d ? out_idx : in_idx;
        const long coloff = (long)d * 960;
        // ---- stage V ----
        #pragma unroll
        for (int v = tid; v < 640; v += 320) {
            const int row = v / 40, c8 = (v % 40) * 8;
            const int src = (row == 0) ? node : idx[node * DDEG + row - 1];
            *(bf16x8*)&v_s[row][c8] = *(const bf16x8*)(P + (long)src * PCOLS + coloff + 640 + c8);
        }
        // ---- QK^T direct from global ----
        const int msrc = (lr == 0) ? node : idx[node * DDEG + lr - 1];
        const nbf* prow = P + (long)msrc * PCOLS + coloff;
        f32x4 sc = {0.f, 0.f, 0.f, 0.f};
        #pragma unroll
        for (int c = 0; c < 2; ++c) {
            bf16x8 aq = *(const bf16x8*)(prow + wave * 64 + c * 32 + lq * 8);
            bf16x8 bk = *(const bf16x8*)(prow + 320 + wave * 64 + c * 32 + lq * 8);
            sc = __builtin_amdgcn_mfma_f32_16x16x32_bf16(aq, bk, sc, 0, 0, 0);
        }
        // ---- softmax over m (= lane&15) ----
        float pr[4], mx4[4], sm4[4];
        #pragma unroll
        for (int r = 0; r < 4; ++r) { pr[r] = sc[r] * 0.125f; mx4[r] = pr[r]; }
        #pragma unroll
        for (int msk = 8; msk >= 1; msk >>= 1)
            #pragma unroll
            for (int r = 0; r < 4; ++r) mx4[r] = fmaxf(mx4[r], __shfl_xor(mx4[r], msk));
        #pragma unroll
        for (int r = 0; r < 4; ++r) { pr[r] = __expf(pr[r] - mx4[r]); sm4[r] = pr[r]; }
        #pragma unroll
        for (int msk = 8; msk >= 1; msk >>= 1)
            #pragma unroll
            for (int r = 0; r < 4; ++r) sm4[r] += __shfl_xor(sm4[r], msk);
        #pragma unroll
        for (int r = 0; r < 4; ++r) p_s[wave][lq * 4 + r][lr] = (nbf)(pr[r] / sm4[r]);
        union { bf16x8 v8; nbf e[8]; } pf;
        #pragma unroll
        for (int j = 0; j < 8; ++j) pf.e[j] = (nbf)0.f;
        if (lq < 2) pf.v8 = *(const bf16x8*)&p_s[wave][lr][lq * 8];
        __syncthreads();                            // v_s ready
        // ---- AV + s-partials ----
        float spart = 0.f;
        #pragma unroll
        for (int t = 0; t < 4; ++t) {
            const int e0 = wave * 64 + t * 16;
            union { bf16x8 v8; nbf e[8]; } af;
            #pragma unroll
            for (int j = 0; j < 8; ++j) af.e[j] = (nbf)0.f;
            if (lq < 2) {
                #pragma unroll
                for (int j = 0; j < 8; ++j) af.e[j] = v_s[lq * 8 + j][e0 + lr];
            }
            f32x4 ov = {0.f, 0.f, 0.f, 0.f};
            ov = __builtin_amdgcn_mfma_f32_16x16x32_bf16(af.v8, pf.v8, ov, 0, 0, 0);
            union { unsigned long long u; nbf e[4]; } o4;
            #pragma unroll
            for (int r = 0; r < 4; ++r) o4.e[r] = (nbf)ov[r];
            *(unsigned long long*)&o_s[d * 16 + lr][e0 + lq * 4] = o4.u;
            f32x4 tv = *(const f32x4*)(Trow + d * 320 + e0 + lq * 4);
            spart += ov[0] * tv[0] + ov[1] * tv[1] + ov[2] * tv[2] + ov[3] * tv[3];
        }
        spart += __shfl_xor(spart, 16);
        spart += __shfl_xor(spart, 32);
        if (lq == 0) s_red[d][lr][wave] = spart;
    }
    __syncthreads();
    if (tid < 32) {
        const int d = tid >> 4, m = tid & 15;
        float s = 0.f;
        #pragma unroll
        for (int w = 0; w < NH; ++w) s += s_red[d][m][w];
        s += Trow[640 + d];
        s_fin[tid] = s * 0.05590169943749474f;
    }
    __syncthreads();
    float mx = -1e30f;
    #pragma unroll 4
    for (int m = 0; m < 32; ++m) mx = fmaxf(mx, s_fin[m]);
    float esum = 0.f, a_in = 0.f, a_out = 0.f;
    #pragma unroll 4
    for (int m = 0; m < 32; ++m) {
        float e = __expf(s_fin[m] - mx);
        esum += e;
        if (m < 16) a_in += e; else a_out += e;
    }
    const float inv = 1.f / esum;
    a_in *= inv; a_out *= inv;
    if (tid < 32) a_s[tid] = __expf(s_fin[tid] - mx) * inv;
    __syncthreads();
    // ---- g = A-weighted sums of O rows ----
    #pragma unroll
    for (int v = tid; v < 640; v += 320) {
        const int mbase = (v < 320) ? 0 : 16;
        const int e = (v < 320) ? v : v - 320;
        float g = 0.f;
        #pragma unroll
        for (int m2 = 0; m2 < 16; ++m2)
            g += a_s[mbase + m2] * (float)o_s[mbase + m2][e];
        g_s[v] = g;
    }
    __syncthreads();
    // ---- projection: j = tid>>3, 8 lanes split e ----
    const int j = tid >> 3, sub = tid & 7;
    if (j < OUTD) {
        const nbf* u_in  = Ut + (long)j * EE;
        const nbf* u_out = Ut + (long)(32 + j) * EE;
        float acc = 0.f;
        for (int c = sub; c < 40; c += 8) {
            bf16x8 uv = *(const bf16x8*)(u_in + c * 8);
            bf16x8 uo = *(const bf16x8*)(u_out + c * 8);
            #pragma unroll
            for (int jj = 0; jj < 8; ++jj) {
                acc += g_s[c * 8 + jj] * (float)uv[jj];
                acc += g_s[320 + c * 8 + jj] * (float)uo[jj];
            }
        }
        acc += __shfl_down(acc, 4, 8);
        acc += __shfl_down(acc, 2, 8);
        acc += __shfl_down(acc, 1, 8);
        if (sub == 0) {
            float r = acc + a_in * WWT[(long)j * KF + 640]
                    + a_out * WWT[(long)j * KF + 641] + bfin[j];
            r = r > 0.f ? r : expm1f(r);
            if (*flag) ((bf16*)out)[(long)node * OUTD + j] = __float2bfloat16(r);
            else       ((float*)out)[(long)node * OUTD + j] = r;
        }
    }
}

// ---------------------------------------------------------------------------
extern "C" void kernel_launch(void* const* d_in, const int* in_sizes, int n_in,
                              void* d_out, int out_size, void* d_ws, size_t ws_size,
                              hipStream_t stream)
{
    const int* in_idx  = (const int*)d_in[1];
    const int* out_idx = (const int*)d_in[2];

    char* p = (char*)d_ws;
    auto alloc = [&](size_t bytes) { char* r = p; p += (bytes + 255) & ~(size_t)255; return r; };
    const size_t EE2 = (size_t)EE * EE;
    int*   flag       = (int*)alloc(256);
    nbf*   X_bf       = (nbf*)alloc((size_t)NNODE * EE * 2);
    nbf*   qkvw6_bf   = (nbf*)alloc(6 * EE2 * 2);     // [in q,k,v | out q,k,v]
    nbf*   Wg6_bf     = (nbf*)alloc(6 * EE2 * 2);     // in_Wq..out_Wv
    nbf*   qkvw_fin_bf= (nbf*)alloc(3 * EE2 * 2);
    nbf*   owT        = (nbf*)alloc(3 * EE2 * 2);     // [in^T | out^T | fin^T]
    float* qkvw_fin_f = (float*)alloc(3 * EE2 * 4);
    float* qkvb_fin_f = (float*)alloc(3 * EE * 4);
    float* bcat       = (float*)alloc(PCOLS * 4);
    float* ob_in_f    = (float*)alloc(EE * 4);
    float* ob_out_f   = (float*)alloc(EE * 4);
    float* ob_fin_f   = (float*)alloc(EE * 4);
    float* W_f        = (float*)alloc((size_t)EE * OUTD * 4);
    float* ow_fin_f   = (float*)alloc(EE2 * 4);
    // composed
    nbf*   AcatT  = (nbf*)alloc((size_t)PCOLS * EE * 2);   // [1920][320]
    nbf*   Qc_bf  = (nbf*)alloc(EE2 * 2);
    nbf*   Kcat   = (nbf*)alloc((size_t)KF * EE * 2);      // [642][320]
    float* bqc_in = (float*)alloc(EE * 4);
    nbf*   M2T    = (nbf*)alloc((size_t)KF * EE * 2);      // [642][320]
    float* bT     = (float*)alloc(KF * 4);
    nbf*   VcatN  = (nbf*)alloc((size_t)KF * EE * 2);      // [642][320]
    nbf*   WfinT  = (nbf*)alloc((size_t)OUTD * EE * 2);    // [30][320]
    float* WWT    = (float*)alloc((size_t)OUTD * KF * 4);  // [30][642]
    float* bfin   = (float*)alloc(64 * 4);
    nbf*   Ut     = (nbf*)alloc((size_t)64 * EE * 2);      // [64][320]
    nbf*   P      = (nbf*)alloc((size_t)NNODE * PCOLS * 2);
    nbf*   Orow0  = (nbf*)alloc((size_t)NNODE * EE * 2);   // [10000][320]
    float* Tm     = (float*)alloc((size_t)NNODE * TST * 4);// [10000][644]

    dim3 blk(256);
    // ---- detect dtype + normalize inputs ----
    detect_dtype_kernel<<<1, blk, 0, stream>>>((const unsigned int*)d_in[0], flag);
    convert_bf_kernel<<<(NNODE * EE + 255) / 256, blk, 0, stream>>>(d_in[0], X_bf, NNODE * EE, flag);
    ConvTab ct;
    int s = 0;
    auto seg = [&](const void* src, void* dst, int n, int tobf) {
        ct.src[s] = src; ct.dst[s] = dst; ct.n[s] = n; ct.tobf[s] = tobf; ++s;
    };
    seg(d_in[6],  qkvw6_bf,           (int)(3 * EE2), 1);
    seg(d_in[13], qkvw6_bf + 3 * EE2, (int)(3 * EE2), 1);
    seg(d_in[3],  Wg6_bf + 0 * EE2, (int)EE2, 1);
    seg(d_in[4],  Wg6_bf + 1 * EE2, (int)EE2, 1);
    seg(d_in[5],  Wg6_bf + 2 * EE2, (int)EE2, 1);
    seg(d_in[10], Wg6_bf + 3 * EE2, (int)EE2, 1);
    seg(d_in[11], Wg6_bf + 4 * EE2, (int)EE2, 1);
    seg(d_in[12], Wg6_bf + 5 * EE2, (int)EE2, 1);
    seg(d_in[17], qkvw_fin_bf, (int)(3 * EE2), 1);
    seg(d_in[17], qkvw_fin_f,  (int)(3 * EE2), 0);
    seg(d_in[18], qkvb_fin_f, 3 * EE, 0);
    seg(d_in[7],  bcat,       3 * EE, 0);
    seg(d_in[14], bcat + 960, 3 * EE, 0);
    seg(d_in[9],  ob_in_f,  EE, 0);
    seg(d_in[16], ob_out_f, EE, 0);
    seg(d_in[20], ob_fin_f, EE, 0);
    seg(d_in[21], W_f, EE * OUTD, 0);
    seg(d_in[19], ow_fin_f, (int)EE2, 0);
    convert_batch_kernel<<<dim3((3 * (int)EE2 + 255) / 256, NSEG), blk, 0, stream>>>(ct, flag);
    transpose3_kernel<<<dim3(10, 10, 3), blk, 0, stream>>>(d_in[8], d_in[15], d_in[19], owT, flag);

    // ---- compose stage 1: 11 independent 320^3 GEMMs in ONE launch ----
    JobTab jt;
    for (int g = 0; g < 6; ++g) {           // AcatT[g] = qkvw6[g] @ Wg6[g]^T
        jt.A[g] = qkvw6_bf + (size_t)g * EE2;
        jt.B[g] = Wg6_bf + (size_t)g * EE2;
        jt.C[g] = AcatT + (size_t)g * EE2;
    }
    jt.A[6] = owT;             jt.B[6] = qkvw_fin_bf;                      jt.C[6] = Qc_bf;   // Qc
    jt.A[7] = owT;             jt.B[7] = qkvw_fin_bf + (size_t)320 * EE;   jt.C[7] = Kcat;    // Kcat in
    jt.A[8] = owT + EE2;       jt.B[8] = qkvw_fin_bf + (size_t)320 * EE;   jt.C[8] = Kcat + (size_t)320 * EE;
    jt.A[9] = owT;             jt.B[9] = qkvw_fin_bf + (size_t)640 * EE;   jt.C[9] = VcatN;   // VcatN in
    jt.A[10]= owT + EE2;       jt.B[10]= qkvw_fin_bf + (size_t)640 * EE;   jt.C[10]= VcatN + (size_t)320 * EE;
    gemm_mfma_jobs<<<dim3(3, 3, NJOB), blk, 0, stream>>>(jt);
    compose_bias_kernel<<<5, 320, 0, stream>>>(ob_in_f, ob_out_f, qkvw_fin_f, qkvb_fin_f,
                                               bqc_in, Kcat, VcatN);
    // M2T = Kcat @ Qc^T
    gemm_mfma<bf16><<<dim3(3, 6), blk, 0, stream>>>(
        Kcat, EE, Qc_bf, EE, nullptr, (bf16*)M2T, EE, KF, EE, EE);
    compose_bT<<<3, blk, 0, stream>>>(bqc_in, Kcat, bT);
    // WfinT[j][e] = sum_a W[a][j] * fin_o_w[a][e]
    gemm_k<true, false, bf16><<<dim3(5, 1), blk, 0, stream>>>(
        W_f, OUTD, ow_fin_f, EE, nullptr, (bf16*)WfinT, EE, OUTD, EE, EE);
    // WWT[j][c] = sum_e WfinT[j][e] * VcatN[c][e]
    gemm_mfma<float><<<dim3(6, 1), blk, 0, stream>>>(
        WfinT, EE, VcatN, EE, nullptr, WWT, KF, OUTD, KF, EE);
    compose_bfin<<<1, 64, 0, stream>>>(ob_fin_f, W_f, bfin);
    ut_prep_kernel<<<(64 * EE + 255) / 256, blk, 0, stream>>>(WWT, Ut);

    // ---- P = X @ Acat + bcat  (MFMA) ----
    gemm_mfma<bf16><<<dim3(PCOLS / 128, (NNODE + 127) / 128), blk, 0, stream>>>(
        X_bf, EE, AcatT, EE, bcat, (bf16*)P, PCOLS, NNODE, PCOLS, EE);

    // ---- row0 in-attention -> Orow0 ----
    row0_kernel<<<NNODE / 4, blk, 0, stream>>>(P, in_idx, Orow0);

    // ---- T = Orow0 @ M2T + bT  (padded stride TST) ----
    gemm_mfma<float><<<dim3((KF + 127) / 128, (NNODE + 127) / 128), blk, 0, stream>>>(
        Orow0, EE, M2T, EE, bT, Tm, TST, NNODE, KF, EE);

    // ---- fused attention + final + projection, one block per node ----
    mega_attn_kernel<<<NNODE, dim3(320), 0, stream>>>(
        P, in_idx, out_idx, Tm, Ut, WWT, bfin, d_out, flag);
}

// Round 10
// 497.054 us; speedup vs baseline: 1.1942x; 1.1942x over previous
//
#include <hip/hip_runtime.h>
#include <hip/hip_bf16.h>

typedef __hip_bfloat16 bf16;
typedef __bf16 nbf;
typedef nbf bf16x8 __attribute__((ext_vector_type(8)));
typedef float f32x4 __attribute__((ext_vector_type(4)));

#define NNODE 10000
#define DDEG  15
#define EE    320
#define LL    16
#define NH    5
#define HD    64
#define OUTD  30
#define PCOLS 1920   // 6*E : [Qin|Kin|Vin|Qout|Kout|Vout]
#define KF    642    // 2*E + 2 (alpha columns)
#define TSTB  648    // padded bf16 T row stride (16B-aligned rows)

// ---------------------------------------------------------------------------
// dtype detection: bf16 data -> low-16 exponent field clustered in [100,140]
// ---------------------------------------------------------------------------
__global__ void detect_dtype_kernel(const unsigned int* __restrict__ X, int* __restrict__ flag)
{
    __shared__ int cnt;
    if (threadIdx.x == 0) cnt = 0;
    __syncthreads();
    int local = 0;
    for (int i = threadIdx.x; i < 1024; i += 256) {
        unsigned int lo = X[i] & 0xFFFFu;
        int e = (int)((lo >> 7) & 0xFFu);
        if (e >= 100 && e <= 140) local++;
    }
    atomicAdd(&cnt, local);
    __syncthreads();
    if (threadIdx.x == 0) *flag = (cnt > 512) ? 1 : 0;
}

__global__ void convert_bf_kernel(const void* __restrict__ src, nbf* __restrict__ dst,
                                  int n, const int* __restrict__ flag)
{
    int i = blockIdx.x * 256 + threadIdx.x;
    if (i >= n) return;
    if (*flag) dst[i] = ((const nbf*)src)[i];
    else       dst[i] = (nbf)(((const float*)src)[i]);
}

#define NSEG 18
struct ConvTab {
    const void* src[NSEG];
    void*       dst[NSEG];
    int         n[NSEG];
    int         tobf[NSEG];
};

__global__ void convert_batch_kernel(ConvTab t, const int* __restrict__ flag)
{
    const int seg = blockIdx.y;
    const int i = blockIdx.x * 256 + threadIdx.x;
    if (i >= t.n[seg]) return;
    float v = (*flag) ? (float)(((const nbf*)t.src[seg])[i]) : ((const float*)t.src[seg])[i];
    if (t.tobf[seg]) ((nbf*)t.dst[seg])[i] = (nbf)v;
    else             ((float*)t.dst[seg])[i] = v;
}

// 3 batched 320x320 transposes: dst[a][e] = src[e][a] (bf16 out)
__global__ __launch_bounds__(256) void transpose3_kernel(const void* s0, const void* s1,
        const void* s2, nbf* __restrict__ dstbase, const int* __restrict__ flag)
{
    const void* src = (blockIdx.z == 0) ? s0 : (blockIdx.z == 1) ? s1 : s2;
    nbf* dst = dstbase + (size_t)blockIdx.z * EE * EE;
    __shared__ nbf tile[32][33];
    const int bx = blockIdx.x * 32, by = blockIdx.y * 32;
    const int tx = threadIdx.x & 31, ty = threadIdx.x >> 5;
    const int f = *flag;
    #pragma unroll
    for (int i = 0; i < 4; ++i) {
        const int r = by + ty + i * 8;
        float v = f ? (float)(((const nbf*)src)[(long)r * EE + bx + tx])
                    : ((const float*)src)[(long)r * EE + bx + tx];
        tile[ty + i * 8][tx] = (nbf)v;
    }
    __syncthreads();
    #pragma unroll
    for (int i = 0; i < 4; ++i) {
        const int r = bx + ty + i * 8;
        dst[(long)r * EE + by + tx] = tile[tx][ty + i * 8];
    }
}

__device__ __forceinline__ void stor(float* p, float v) { *p = v; }
__device__ __forceinline__ void stor(bf16* p, float v) { *p = __float2bfloat16(v); }

// ---------------------------------------------------------------------------
// VALU 64x64 GEMM (tiny compose ops; f32 in)
// ---------------------------------------------------------------------------
template<bool AT, bool BT, typename OT>
__global__ __launch_bounds__(256) void gemm_k(const float* __restrict__ A, int lda,
                       const float* __restrict__ B, int ldb,
                       const float* __restrict__ bias,
                       OT* __restrict__ C, int ldc, int M, int Nn, int K)
{
    __shared__ float As[16][65];
    __shared__ float Bs[16][65];
    const int tid = threadIdx.x;
    const int tx = tid & 15, ty = tid >> 4;
    const int n0 = blockIdx.x * 64, m0 = blockIdx.y * 64;
    float acc[4][4] = {};
    for (int k0 = 0; k0 < K; k0 += 16) {
        if constexpr (AT) {
            for (int i = tid; i < 1024; i += 256) {
                int kk = i >> 6, r = i & 63;
                int gm = m0 + r, gk = k0 + kk;
                As[kk][r] = (gm < M && gk < K) ? A[(long)gk * lda + gm] : 0.f;
            }
        } else {
            for (int i = tid; i < 1024; i += 256) {
                int r = i >> 4, kk = i & 15;
                int gm = m0 + r, gk = k0 + kk;
                As[kk][r] = (gm < M && gk < K) ? A[(long)gm * lda + gk] : 0.f;
            }
        }
        if constexpr (BT) {
            for (int i = tid; i < 1024; i += 256) {
                int r = i >> 4, kk = i & 15;
                int gn = n0 + r, gk = k0 + kk;
                Bs[kk][r] = (gn < Nn && gk < K) ? B[(long)gn * ldb + gk] : 0.f;
            }
        } else {
            for (int i = tid; i < 1024; i += 256) {
                int kk = i >> 6, c = i & 63;
                int gk = k0 + kk, gn = n0 + c;
                Bs[kk][c] = (gk < K && gn < Nn) ? B[(long)gk * ldb + gn] : 0.f;
            }
        }
        __syncthreads();
        #pragma unroll
        for (int kk = 0; kk < 16; ++kk) {
            float ra[4], rb[4];
            #pragma unroll
            for (int a = 0; a < 4; ++a) ra[a] = As[kk][ty * 4 + a];
            #pragma unroll
            for (int b = 0; b < 4; ++b) rb[b] = Bs[kk][tx * 4 + b];
            #pragma unroll
            for (int a = 0; a < 4; ++a)
                #pragma unroll
                for (int b = 0; b < 4; ++b)
                    acc[a][b] += ra[a] * rb[b];
        }
        __syncthreads();
    }
    #pragma unroll
    for (int a = 0; a < 4; ++a) {
        int gm = m0 + ty * 4 + a;
        if (gm >= M) continue;
        #pragma unroll
        for (int b = 0; b < 4; ++b) {
            int gn = n0 + tx * 4 + b;
            if (gn >= Nn) continue;
            float v = acc[a][b] + (bias ? bias[gn] : 0.f);
            stor(&C[(long)gm * ldc + gn], v);
        }
    }
}

// ---------------------------------------------------------------------------
// MFMA bf16 GEMM: C[M,N] = A[M,K] @ Bt[N,K]^T + bias. 128x128 tile, BK=32.
// ---------------------------------------------------------------------------
template<typename OT>
__global__ __launch_bounds__(256) void gemm_mfma(const nbf* __restrict__ A, int lda,
        const nbf* __restrict__ Bt, int ldb, const float* __restrict__ bias,
        OT* __restrict__ C, int ldc, int M, int Nn, int K)
{
    __shared__ __align__(16) nbf As[128][40];
    __shared__ __align__(16) nbf Bs[128][40];
    const int tid = threadIdx.x;
    const int lane = tid & 63, wave = tid >> 6;
    const int wr = (wave >> 1) * 64, wc = (wave & 1) * 64;
    const int m0 = blockIdx.y * 128, n0 = blockIdx.x * 128;
    const int lr = lane & 15, lq = lane >> 4;
    f32x4 acc[4][4];
    #pragma unroll
    for (int i = 0; i < 4; ++i)
        #pragma unroll
        for (int j = 0; j < 4; ++j) { acc[i][j][0]=0.f; acc[i][j][1]=0.f; acc[i][j][2]=0.f; acc[i][j][3]=0.f; }

    for (int k0 = 0; k0 < K; k0 += 32) {
        #pragma unroll
        for (int v = tid; v < 512; v += 256) {
            const int row = v >> 2, cv = (v & 3) << 3;
            const int gk = k0 + cv;
            {
                const int gm = m0 + row;
                bf16x8 val;
                if (gm < M && gk + 8 <= K) {
                    val = *(const bf16x8*)(A + (long)gm * lda + gk);
                } else {
                    union { bf16x8 v8; nbf e[8]; } u;
                    #pragma unroll
                    for (int j = 0; j < 8; ++j) {
                        float x = (gm < M && gk + j < K) ? (float)A[(long)gm * lda + gk + j] : 0.f;
                        u.e[j] = (nbf)x;
                    }
                    val = u.v8;
                }
                *(bf16x8*)&As[row][cv] = val;
            }
            {
                const int gn = n0 + row;
                bf16x8 val;
                if (gn < Nn && gk + 8 <= K) {
                    val = *(const bf16x8*)(Bt + (long)gn * ldb + gk);
                } else {
                    union { bf16x8 v8; nbf e[8]; } u;
                    #pragma unroll
                    for (int j = 0; j < 8; ++j) {
                        float x = (gn < Nn && gk + j < K) ? (float)Bt[(long)gn * ldb + gk + j] : 0.f;
                        u.e[j] = (nbf)x;
                    }
                    val = u.v8;
                }
                *(bf16x8*)&Bs[row][cv] = val;
            }
        }
        __syncthreads();
        bf16x8 af[4], bfv[4];
        #pragma unroll
        for (int i = 0; i < 4; ++i) af[i] = *(const bf16x8*)&As[wr + i * 16 + lr][lq * 8];
        #pragma unroll
        for (int j = 0; j < 4; ++j) bfv[j] = *(const bf16x8*)&Bs[wc + j * 16 + lr][lq * 8];
        #pragma unroll
        for (int i = 0; i < 4; ++i)
            #pragma unroll
            for (int j = 0; j < 4; ++j)
                acc[i][j] = __builtin_amdgcn_mfma_f32_16x16x32_bf16(af[i], bfv[j], acc[i][j], 0, 0, 0);
        __syncthreads();
    }
    #pragma unroll
    for (int i = 0; i < 4; ++i) {
        #pragma unroll
        for (int j = 0; j < 4; ++j) {
            const int gn = n0 + wc + j * 16 + lr;
            if (gn >= Nn) continue;
            const float bv = bias ? bias[gn] : 0.f;
            #pragma unroll
            for (int r = 0; r < 4; ++r) {
                const int gm = m0 + wr + i * 16 + lq * 4 + r;
                if (gm < M) stor(&C[(long)gm * ldc + gn], acc[i][j][r] + bv);
            }
        }
    }
}

// ---------------------------------------------------------------------------
// Batched 320x320x320 bf16 GEMMs (compose stage 1): C[j] = A[j] @ B[j]^T
// ---------------------------------------------------------------------------
#define NJOB 11
struct JobTab {
    const nbf* A[NJOB];
    const nbf* B[NJOB];
    nbf*       C[NJOB];
};

__global__ __launch_bounds__(256) void gemm_mfma_jobs(JobTab jt)
{
    const nbf* A  = jt.A[blockIdx.z];
    const nbf* Bt = jt.B[blockIdx.z];
    nbf* C        = jt.C[blockIdx.z];
    __shared__ __align__(16) nbf As[128][40];
    __shared__ __align__(16) nbf Bs[128][40];
    const int tid = threadIdx.x;
    const int lane = tid & 63, wave = tid >> 6;
    const int wr = (wave >> 1) * 64, wc = (wave & 1) * 64;
    const int m0 = blockIdx.y * 128, n0 = blockIdx.x * 128;
    const int lr = lane & 15, lq = lane >> 4;
    f32x4 acc[4][4];
    #pragma unroll
    for (int i = 0; i < 4; ++i)
        #pragma unroll
        for (int j = 0; j < 4; ++j) { acc[i][j][0]=0.f; acc[i][j][1]=0.f; acc[i][j][2]=0.f; acc[i][j][3]=0.f; }
    for (int k0 = 0; k0 < EE; k0 += 32) {
        #pragma unroll
        for (int v = tid; v < 512; v += 256) {
            const int row = v >> 2, cv = (v & 3) << 3;
            const int gk = k0 + cv;
            const int gm = m0 + row, gn = n0 + row;
            bf16x8 va = {}, vb = {};
            if (gm < EE) va = *(const bf16x8*)(A + (long)gm * EE + gk);
            if (gn < EE) vb = *(const bf16x8*)(Bt + (long)gn * EE + gk);
            *(bf16x8*)&As[row][cv] = va;
            *(bf16x8*)&Bs[row][cv] = vb;
        }
        __syncthreads();
        bf16x8 af[4], bfv[4];
        #pragma unroll
        for (int i = 0; i < 4; ++i) af[i] = *(const bf16x8*)&As[wr + i * 16 + lr][lq * 8];
        #pragma unroll
        for (int j = 0; j < 4; ++j) bfv[j] = *(const bf16x8*)&Bs[wc + j * 16 + lr][lq * 8];
        #pragma unroll
        for (int i = 0; i < 4; ++i)
            #pragma unroll
            for (int j = 0; j < 4; ++j)
                acc[i][j] = __builtin_amdgcn_mfma_f32_16x16x32_bf16(af[i], bfv[j], acc[i][j], 0, 0, 0);
        __syncthreads();
    }
    #pragma unroll
    for (int i = 0; i < 4; ++i)
        #pragma unroll
        for (int j = 0; j < 4; ++j) {
            const int gn = n0 + wc + j * 16 + lr;
            if (gn >= EE) continue;
            #pragma unroll
            for (int r = 0; r < 4; ++r) {
                const int gm = m0 + wr + i * 16 + lq * 4 + r;
                if (gm < EE) C[(long)gm * EE + gn] = (nbf)acc[i][j][r];
            }
        }
}

// ---------------------------------------------------------------------------
// which: 0->bqc_in  1->Kcat row640  2->Kcat row641  3->VcatN row640  4->row641
// ---------------------------------------------------------------------------
__global__ __launch_bounds__(320) void compose_bias_kernel(
        const float* __restrict__ in_o_b, const float* __restrict__ out_o_b,
        const float* __restrict__ fin_qkv_w, const float* __restrict__ fin_qkv_b,
        float* __restrict__ bqc_in, nbf* __restrict__ Kcat, nbf* __restrict__ VcatN)
{
    const int which = blockIdx.x;
    const int b = threadIdx.x;
    const float* ob = (which == 2 || which == 4) ? out_o_b : in_o_b;
    const int off = (which == 0) ? 0 : (which <= 2) ? 320 : 640;
    float acc = fin_qkv_b[off + b];
    const float* wr = fin_qkv_w + (long)(off + b) * EE;
    for (int e = 0; e < EE; ++e) acc += ob[e] * wr[e];
    if (which == 0)      bqc_in[b] = acc;
    else if (which == 1) Kcat[(long)640 * EE + b] = (nbf)acc;
    else if (which == 2) Kcat[(long)641 * EE + b] = (nbf)acc;
    else if (which == 3) VcatN[(long)640 * EE + b] = (nbf)acc;
    else                 VcatN[(long)641 * EE + b] = (nbf)acc;
}

__global__ void compose_bfin(const float* __restrict__ fin_o_b, const float* __restrict__ W,
                             float* __restrict__ bfin)
{
    int j = threadIdx.x;
    if (j >= OUTD) return;
    float acc = 0.f;
    for (int e = 0; e < EE; ++e) acc += fin_o_b[e] * W[e * OUTD + j];
    bfin[j] = acc;
}

__global__ void compose_bT(const float* __restrict__ bqc, const nbf* __restrict__ Kcat,
                           float* __restrict__ bT)
{
    int c = blockIdx.x * 256 + threadIdx.x;
    if (c >= KF) return;
    const nbf* kr = Kcat + (long)c * EE;
    float acc = 0.f;
    for (int b = 0; b < EE; ++b) acc += bqc[b] * (float)kr[b];
    bT[c] = acc;
}

// Ut[64][320] bf16: rows 0..29 = WWT[:,0:320] (U_in), rows 32..61 = WWT[:,320:640]
__global__ void ut_prep_kernel(const float* __restrict__ WWT, nbf* __restrict__ Ut)
{
    int v = blockIdx.x * 256 + threadIdx.x;
    if (v >= 64 * EE) return;
    int n = v / EE, e = v % EE;
    float val = 0.f;
    if (n < OUTD) val = WWT[(long)n * KF + e];
    else if (n >= 32 && n < 32 + OUTD) val = WWT[(long)(n - 32) * KF + 320 + e];
    Ut[v] = (nbf)val;
}

// ---------------------------------------------------------------------------
// row0: per-node single-query in-dir attention -> Orow0[node][320] (bf16)
// ---------------------------------------------------------------------------
__global__ __launch_bounds__(256) void row0_kernel(const nbf* __restrict__ P,
        const int* __restrict__ in_idx, nbf* __restrict__ Orow0)
{
    const int tid = threadIdx.x, lane = tid & 63, wave = tid >> 6;
    const int node = blockIdx.x * 4 + wave;
    __shared__ float a_sh[4][16];
    __shared__ int srcs_sh[4][16];
    const int m = lane & 15, q4 = lane >> 4;
    const int src = (m == 0) ? node : in_idx[node * DDEG + m - 1];
    if (q4 == 0) srcs_sh[wave][m] = src;
    const nbf* qrow = P + (long)node * PCOLS;
    const nbf* krow = P + (long)src * PCOLS + 320;
    #pragma unroll
    for (int h = 0; h < NH; ++h) {
        float s = 0.f;
        bf16x8 q1 = *(const bf16x8*)(qrow + h * 64 + q4 * 16);
        bf16x8 q2 = *(const bf16x8*)(qrow + h * 64 + q4 * 16 + 8);
        bf16x8 k1 = *(const bf16x8*)(krow + h * 64 + q4 * 16);
        bf16x8 k2 = *(const bf16x8*)(krow + h * 64 + q4 * 16 + 8);
        #pragma unroll
        for (int j = 0; j < 8; ++j)
            s += (float)q1[j] * (float)k1[j] + (float)q2[j] * (float)k2[j];
        s += __shfl_xor(s, 16);
        s += __shfl_xor(s, 32);
        s *= 0.125f;
        float mxv = s;
        #pragma unroll
        for (int msk = 8; msk >= 1; msk >>= 1) mxv = fmaxf(mxv, __shfl_xor(mxv, msk));
        float e = __expf(s - mxv);
        float es = e;
        #pragma unroll
        for (int msk = 8; msk >= 1; msk >>= 1) es += __shfl_xor(es, msk);
        if (q4 == 0) a_sh[wave][m] = e / es;
        float o = 0.f;
        #pragma unroll
        for (int mm = 0; mm < 16; ++mm)
            o += a_sh[wave][mm] * (float)P[(long)srcs_sh[wave][mm] * PCOLS + 640 + h * 64 + lane];
        Orow0[(long)node * EE + h * 64 + lane] = (nbf)o;
    }
}

// ---------------------------------------------------------------------------
// attn_y: per (node,dir) block (320 thr = 5 waves = heads). v4 attention core,
// then Y[m][n] = O[m]·[U_d | T_half]^T computed per-wave over its 64-e slab
// (O staged into consumed V-slab; T smuggled as B-column 31), LDS-reduced,
// written as 512 f32 per (node,dir). O never touches global memory.
// ---------------------------------------------------------------------------
__global__ __launch_bounds__(320) void attn_y_kernel(const nbf* __restrict__ P,
        const int* __restrict__ in_idx, const int* __restrict__ out_idx,
        const nbf* __restrict__ Tb, const nbf* __restrict__ Ut,
        float* __restrict__ Ygl, int node_base)
{
    const int bx = blockIdx.x;
    const int lnode = bx >> 1, d = bx & 1;
    const int node = node_base + lnode;
    const int tid = threadIdx.x;
    const int lane = tid & 63, wave = tid >> 6;      // wave == head
    __shared__ __align__(16) nbf v_s[16][328];       // V, then O overlay per slab
    __shared__ __align__(16) nbf p_s[NH][16][16];
    __shared__ float Yp[NH][16][32];
    const int* idx = d ? out_idx : in_idx;
    const long coloff = (long)d * 960;
    const int lr = lane & 15, lq = lane >> 4;
    // ---- stage V ----
    #pragma unroll
    for (int v = tid; v < 640; v += 320) {
        const int row = v / 40, c8 = (v % 40) * 8;
        const int src = (row == 0) ? node : idx[node * DDEG + row - 1];
        *(bf16x8*)&v_s[row][c8] = *(const bf16x8*)(P + (long)src * PCOLS + coloff + 640 + c8);
    }
    // ---- Q/K direct from global; QK^T overlaps V staging ----
    const int msrc = (lr == 0) ? node : idx[node * DDEG + lr - 1];
    const nbf* prow = P + (long)msrc * PCOLS + coloff;
    f32x4 sc = {0.f, 0.f, 0.f, 0.f};
    #pragma unroll
    for (int c = 0; c < 2; ++c) {
        bf16x8 aq = *(const bf16x8*)(prow + wave * 64 + c * 32 + lq * 8);
        bf16x8 bk = *(const bf16x8*)(prow + 320 + wave * 64 + c * 32 + lq * 8);
        sc = __builtin_amdgcn_mfma_f32_16x16x32_bf16(aq, bk, sc, 0, 0, 0);
    }
    // ---- softmax over m (= lane&15) ----
    float pr[4], mx4[4], sm4[4];
    #pragma unroll
    for (int r = 0; r < 4; ++r) { pr[r] = sc[r] * 0.125f; mx4[r] = pr[r]; }
    #pragma unroll
    for (int msk = 8; msk >= 1; msk >>= 1)
        #pragma unroll
        for (int r = 0; r < 4; ++r) mx4[r] = fmaxf(mx4[r], __shfl_xor(mx4[r], msk));
    #pragma unroll
    for (int r = 0; r < 4; ++r) { pr[r] = __expf(pr[r] - mx4[r]); sm4[r] = pr[r]; }
    #pragma unroll
    for (int msk = 8; msk >= 1; msk >>= 1)
        #pragma unroll
        for (int r = 0; r < 4; ++r) sm4[r] += __shfl_xor(sm4[r], msk);
    #pragma unroll
    for (int r = 0; r < 4; ++r) p_s[wave][lq * 4 + r][lr] = (nbf)(pr[r] / sm4[r]);
    union { bf16x8 v8; nbf e[8]; } pf;
    #pragma unroll
    for (int j = 0; j < 8; ++j) pf.e[j] = (nbf)0.f;
    if (lq < 2) pf.v8 = *(const bf16x8*)&p_s[wave][lr][lq * 8];
    __syncthreads();   // v_s ready
    // ---- AV; O overlaid into this wave's own (consumed) V col-slab ----
    #pragma unroll
    for (int t = 0; t < 4; ++t) {
        const int e0 = wave * 64 + t * 16;
        union { bf16x8 v8; nbf e[8]; } af;
        #pragma unroll
        for (int j = 0; j < 8; ++j) af.e[j] = (nbf)0.f;
        if (lq < 2) {
            #pragma unroll
            for (int j = 0; j < 8; ++j) af.e[j] = v_s[lq * 8 + j][e0 + lr];
        }
        f32x4 ov = {0.f, 0.f, 0.f, 0.f};
        ov = __builtin_amdgcn_mfma_f32_16x16x32_bf16(af.v8, pf.v8, ov, 0, 0, 0);
        union { unsigned long long u; nbf e[4]; } o4;
        #pragma unroll
        for (int r = 0; r < 4; ++r) o4.e[r] = (nbf)ov[r];
        *(unsigned long long*)&v_s[lr][e0 + lq * 4] = o4.u;   // O[l=lr][e0+lq*4..]
    }
    // ---- Y partials over this wave's 64-e slab (reads own writes, no barrier)
    const nbf* Utd = Ut + (long)d * 32 * EE;
    const nbf* TbRow = Tb + (long)node * TSTB + (long)d * 320;
    f32x4 yacc[2];
    yacc[0][0]=0.f; yacc[0][1]=0.f; yacc[0][2]=0.f; yacc[0][3]=0.f;
    yacc[1][0]=0.f; yacc[1][1]=0.f; yacc[1][2]=0.f; yacc[1][3]=0.f;
    const int e0w = wave * 64;
    #pragma unroll
    for (int c = 0; c < 2; ++c) {
        const int kk = e0w + c * 32 + lq * 8;
        bf16x8 afy = *(const bf16x8*)&v_s[lr][kk];
        #pragma unroll
        for (int nt = 0; nt < 2; ++nt) {
            const int row = nt * 16 + lr;
            const nbf* bp = (row == 31) ? (TbRow + kk) : (Utd + (long)row * EE + kk);
            bf16x8 bfy = *(const bf16x8*)bp;
            yacc[nt] = __builtin_amdgcn_mfma_f32_16x16x32_bf16(afy, bfy, yacc[nt], 0, 0, 0);
        }
    }
    #pragma unroll
    for (int nt = 0; nt < 2; ++nt)
        #pragma unroll
        for (int r = 0; r < 4; ++r)
            Yp[wave][lq * 4 + r][nt * 16 + lr] = yacc[nt][r];
    __syncthreads();
    // ---- cross-wave reduce + coalesced 2KB store ----
    float* yout = Ygl + (long)(lnode * 2 + d) * 512;
    for (int v = tid; v < 512; v += 320) {
        float sme = 0.f;
        #pragma unroll
        for (int w = 0; w < NH; ++w) sme += Yp[w][v >> 5][v & 31];
        yout[v] = sme;
    }
}

// ---------------------------------------------------------------------------
// combine: 4 nodes/block, one wave per node. softmax-32 over s (= Y[.][31]
// + alpha col) then out_j = sum a*Y[.][j] + alpha terms + bfin, ELU.
// ---------------------------------------------------------------------------
__global__ __launch_bounds__(256) void combine_kernel(const float* __restrict__ Ygl,
        const nbf* __restrict__ Tb, const float* __restrict__ WWT,
        const float* __restrict__ bfin, void* __restrict__ out,
        long obase, int cnt, const int* __restrict__ flag)
{
    const int tid = threadIdx.x, lane = tid & 63, wave = tid >> 6;
    const int node = blockIdx.x * 4 + wave;
    const int nodec = (node < cnt) ? node : (cnt - 1);
    __shared__ float Yl[4][1024];
    __shared__ float sf[4][32];
    const float* ysrc = Ygl + (long)nodec * 1024;
    #pragma unroll
    for (int v = lane; v < 1024; v += 64) Yl[wave][v] = ysrc[v];
    if (lane < 32) {
        const int d = lane >> 4, m = lane & 15;
        sf[wave][lane] = (Yl[wave][d * 512 + m * 32 + 31]
                          + (float)Tb[(long)nodec * TSTB + 640 + d]) * 0.05590169943749474f;
    }
    // same-wave LDS ordering: no barrier needed
    float mx = -1e30f;
    #pragma unroll 4
    for (int m = 0; m < 32; ++m) mx = fmaxf(mx, sf[wave][m]);
    float esum = 0.f, a_in = 0.f, a_out = 0.f;
    #pragma unroll 4
    for (int m = 0; m < 32; ++m) {
        float e = __expf(sf[wave][m] - mx);
        esum += e;
        if (m < 16) a_in += e; else a_out += e;
    }
    const float inv = 1.f / esum;
    a_in *= inv; a_out *= inv;
    const int j = lane;
    if (j < OUTD && node < cnt) {
        float acc = 0.f;
        #pragma unroll 4
        for (int dm = 0; dm < 32; ++dm) {
            const int d = dm >> 4, m = dm & 15;
            float a = __expf(sf[wave][dm] - mx) * inv;
            acc += a * Yl[wave][d * 512 + m * 32 + j];
        }
        float r = acc + a_in * WWT[(long)j * KF + 640]
                + a_out * WWT[(long)j * KF + 641] + bfin[j];
        r = r > 0.f ? r : expm1f(r);
        if (*flag) ((bf16*)out)[obase + (long)node * OUTD + j] = __float2bfloat16(r);
        else       ((float*)out)[obase + (long)node * OUTD + j] = r;
    }
}

// ---------------------------------------------------------------------------
extern "C" void kernel_launch(void* const* d_in, const int* in_sizes, int n_in,
                              void* d_out, int out_size, void* d_ws, size_t ws_size,
                              hipStream_t stream)
{
    const int* in_idx  = (const int*)d_in[1];
    const int* out_idx = (const int*)d_in[2];

    char* p = (char*)d_ws;
    auto alloc = [&](size_t bytes) { char* r = p; p += (bytes + 255) & ~(size_t)255; return r; };
    const size_t EE2 = (size_t)EE * EE;
    int*   flag       = (int*)alloc(256);
    nbf*   X_bf       = (nbf*)alloc((size_t)NNODE * EE * 2);
    nbf*   qkvw6_bf   = (nbf*)alloc(6 * EE2 * 2);
    nbf*   Wg6_bf     = (nbf*)alloc(6 * EE2 * 2);
    nbf*   qkvw_fin_bf= (nbf*)alloc(3 * EE2 * 2);
    nbf*   owT        = (nbf*)alloc(3 * EE2 * 2);
    float* qkvw_fin_f = (float*)alloc(3 * EE2 * 4);
    float* qkvb_fin_f = (float*)alloc(3 * EE * 4);
    float* bcat       = (float*)alloc(PCOLS * 4);
    float* ob_in_f    = (float*)alloc(EE * 4);
    float* ob_out_f   = (float*)alloc(EE * 4);
    float* ob_fin_f   = (float*)alloc(EE * 4);
    float* W_f        = (float*)alloc((size_t)EE * OUTD * 4);
    float* ow_fin_f   = (float*)alloc(EE2 * 4);
    // composed
    nbf*   AcatT  = (nbf*)alloc((size_t)PCOLS * EE * 2);
    nbf*   Qc_bf  = (nbf*)alloc(EE2 * 2);
    nbf*   Kcat   = (nbf*)alloc((size_t)KF * EE * 2);
    float* bqc_in = (float*)alloc(EE * 4);
    nbf*   M2T    = (nbf*)alloc((size_t)KF * EE * 2);
    float* bT     = (float*)alloc(KF * 4);
    nbf*   VcatN  = (nbf*)alloc((size_t)KF * EE * 2);
    nbf*   WfinT  = (nbf*)alloc((size_t)OUTD * EE * 2);
    float* WWT    = (float*)alloc((size_t)OUTD * KF * 4);
    float* bfin   = (float*)alloc(64 * 4);
    nbf*   Ut     = (nbf*)alloc((size_t)64 * EE * 2);
    nbf*   P      = (nbf*)alloc((size_t)NNODE * PCOLS * 2);
    nbf*   Orow0  = (nbf*)alloc((size_t)NNODE * EE * 2);
    nbf*   Tb     = (nbf*)alloc((size_t)NNODE * TSTB * 2);  // [10000][648] bf16
    size_t fixed = (size_t)(p - (char*)d_ws);

    const size_t per_node = 1024 * 4;   // Y: 2 dirs x 512 f32
    size_t avail = (ws_size > fixed + 65536) ? (ws_size - fixed - 65536) : 0;
    long chunk_l = (long)(avail / per_node);
    chunk_l = (chunk_l / 4) * 4;
    int chunk = (chunk_l > NNODE) ? NNODE : (chunk_l < 4 ? 4 : (int)chunk_l);
    float* Ygl = (float*)alloc((size_t)chunk * 1024 * 4);

    dim3 blk(256);
    // ---- detect dtype + normalize inputs ----
    detect_dtype_kernel<<<1, blk, 0, stream>>>((const unsigned int*)d_in[0], flag);
    convert_bf_kernel<<<(NNODE * EE + 255) / 256, blk, 0, stream>>>(d_in[0], X_bf, NNODE * EE, flag);
    ConvTab ct;
    int s = 0;
    auto seg = [&](const void* src, void* dst, int n, int tobf) {
        ct.src[s] = src; ct.dst[s] = dst; ct.n[s] = n; ct.tobf[s] = tobf; ++s;
    };
    seg(d_in[6],  qkvw6_bf,           (int)(3 * EE2), 1);
    seg(d_in[13], qkvw6_bf + 3 * EE2, (int)(3 * EE2), 1);
    seg(d_in[3],  Wg6_bf + 0 * EE2, (int)EE2, 1);
    seg(d_in[4],  Wg6_bf + 1 * EE2, (int)EE2, 1);
    seg(d_in[5],  Wg6_bf + 2 * EE2, (int)EE2, 1);
    seg(d_in[10], Wg6_bf + 3 * EE2, (int)EE2, 1);
    seg(d_in[11], Wg6_bf + 4 * EE2, (int)EE2, 1);
    seg(d_in[12], Wg6_bf + 5 * EE2, (int)EE2, 1);
    seg(d_in[17], qkvw_fin_bf, (int)(3 * EE2), 1);
    seg(d_in[17], qkvw_fin_f,  (int)(3 * EE2), 0);
    seg(d_in[18], qkvb_fin_f, 3 * EE, 0);
    seg(d_in[7],  bcat,       3 * EE, 0);
    seg(d_in[14], bcat + 960, 3 * EE, 0);
    seg(d_in[9],  ob_in_f,  EE, 0);
    seg(d_in[16], ob_out_f, EE, 0);
    seg(d_in[20], ob_fin_f, EE, 0);
    seg(d_in[21], W_f, EE * OUTD, 0);
    seg(d_in[19], ow_fin_f, (int)EE2, 0);
    convert_batch_kernel<<<dim3((3 * (int)EE2 + 255) / 256, NSEG), blk, 0, stream>>>(ct, flag);
    transpose3_kernel<<<dim3(10, 10, 3), blk, 0, stream>>>(d_in[8], d_in[15], d_in[19], owT, flag);

    // ---- compose stage 1: 11 independent 320^3 GEMMs in ONE launch ----
    JobTab jt;
    for (int g = 0; g < 6; ++g) {
        jt.A[g] = qkvw6_bf + (size_t)g * EE2;
        jt.B[g] = Wg6_bf + (size_t)g * EE2;
        jt.C[g] = AcatT + (size_t)g * EE2;
    }
    jt.A[6] = owT;             jt.B[6] = qkvw_fin_bf;                      jt.C[6] = Qc_bf;
    jt.A[7] = owT;             jt.B[7] = qkvw_fin_bf + (size_t)320 * EE;   jt.C[7] = Kcat;
    jt.A[8] = owT + EE2;       jt.B[8] = qkvw_fin_bf + (size_t)320 * EE;   jt.C[8] = Kcat + (size_t)320 * EE;
    jt.A[9] = owT;             jt.B[9] = qkvw_fin_bf + (size_t)640 * EE;   jt.C[9] = VcatN;
    jt.A[10]= owT + EE2;       jt.B[10]= qkvw_fin_bf + (size_t)640 * EE;   jt.C[10]= VcatN + (size_t)320 * EE;
    gemm_mfma_jobs<<<dim3(3, 3, NJOB), blk, 0, stream>>>(jt);
    compose_bias_kernel<<<5, 320, 0, stream>>>(ob_in_f, ob_out_f, qkvw_fin_f, qkvb_fin_f,
                                               bqc_in, Kcat, VcatN);
    gemm_mfma<bf16><<<dim3(3, 6), blk, 0, stream>>>(
        Kcat, EE, Qc_bf, EE, nullptr, (bf16*)M2T, EE, KF, EE, EE);
    compose_bT<<<3, blk, 0, stream>>>(bqc_in, Kcat, bT);
    gemm_k<true, false, bf16><<<dim3(5, 1), blk, 0, stream>>>(
        W_f, OUTD, ow_fin_f, EE, nullptr, (bf16*)WfinT, EE, OUTD, EE, EE);
    gemm_mfma<float><<<dim3(6, 1), blk, 0, stream>>>(
        WfinT, EE, VcatN, EE, nullptr, WWT, KF, OUTD, KF, EE);
    compose_bfin<<<1, 64, 0, stream>>>(ob_fin_f, W_f, bfin);
    ut_prep_kernel<<<(64 * EE + 255) / 256, blk, 0, stream>>>(WWT, Ut);

    // ---- P = X @ Acat + bcat  (MFMA) ----
    gemm_mfma<bf16><<<dim3(PCOLS / 128, (NNODE + 127) / 128), blk, 0, stream>>>(
        X_bf, EE, AcatT, EE, bcat, (bf16*)P, PCOLS, NNODE, PCOLS, EE);

    // ---- row0 in-attention -> Orow0 ----
    row0_kernel<<<NNODE / 4, blk, 0, stream>>>(P, in_idx, Orow0);

    // ---- T = Orow0 @ M2T + bT  -> bf16, padded stride TSTB ----
    gemm_mfma<bf16><<<dim3((KF + 127) / 128, (NNODE + 127) / 128), blk, 0, stream>>>(
        Orow0, EE, M2T, EE, bT, (bf16*)Tb, TSTB, NNODE, KF, EE);

    // ---- per-node pipeline (chunked over Y buffer) ----
    for (int base = 0; base < NNODE; base += chunk) {
        int cnt = (NNODE - base < chunk) ? (NNODE - base) : chunk;
        attn_y_kernel<<<2 * cnt, dim3(320), 0, stream>>>(
            P, in_idx, out_idx, Tb, Ut, Ygl, base);
        combine_kernel<<<(cnt + 3) / 4, blk, 0, stream>>>(
            Ygl, Tb + (size_t)base * TSTB, WWT, bfin, d_out, (long)base * OUTD, cnt, flag);
    }
}